// Round 1
// baseline (5444.441 us; speedup 1.0000x reference)
//
#include <hip/hip_runtime.h>
#include <hip/hip_bf16.h>
#include <cstddef>

#define T_SEQ 2048
#define BATCH 64
#define H 128
#define EPS 1e-5f

// ---------- math helpers ----------
__device__ __forceinline__ float sigmoid_f(float x) {
    float e = __expf(-fabsf(x));
    float s = 1.0f / (1.0f + e);
    return (x >= 0.0f) ? s : 1.0f - s;
}
__device__ __forceinline__ float tanh_f(float x) {
    float e = __expf(-2.0f * fabsf(x));
    float t = 1.0f - 2.0f * e / (1.0f + e);
    return (x >= 0.0f) ? t : -t;
}
__device__ __forceinline__ float mish_f(float x) {
    float sp = (x > 15.0f) ? x : log1pf(__expf(x));
    return x * tanh_f(sp);
}

// ---------- input-projection GEMM ----------
// C[(t*B + b)][0..383] = A[(b*T + t)][0..K-1] . W[n][0..K-1] + bias[n]
// A rows indexed (b*T+t) (input layout [B][T][K]); C rows indexed (t*B+b)
// so the scan can read xp[t][b][0..383] contiguously.
// Tiles: TM=128 (t,b)-rows, TN=128 cols, BK=16. 256 threads, 8x8 per thread.
template<int K>
__global__ __launch_bounds__(256, 2)
void proj_kernel(const float* __restrict__ A, const float* __restrict__ W,
                 const float* __restrict__ bias, float* __restrict__ C)
{
    __shared__ float As[16][128];
    __shared__ float Ws[16][128];
    const int n0 = blockIdx.x * 128;
    const int m0 = blockIdx.y * 128;
    const int tid = threadIdx.x;
    const int tx = tid & 15;
    const int ty = tid >> 4;
    float acc[8][8];
    #pragma unroll
    for (int i = 0; i < 8; ++i)
        #pragma unroll
        for (int j = 0; j < 8; ++j) acc[i][j] = 0.0f;

    for (int k0 = 0; k0 < K; k0 += 16) {
        #pragma unroll
        for (int i = 0; i < 2; ++i) {
            const int f = tid + i * 256;       // 0..511 float4 slots
            const int r = f >> 2;              // tile row 0..127
            const int kq = (f & 3) << 2;       // k offset 0,4,8,12
            const int m = m0 + r;              // global C-row (t*64+b)
            const size_t arow = (size_t)(m & 63) * T_SEQ + (m >> 6); // b*T+t
            const float4 av = *reinterpret_cast<const float4*>(&A[arow * K + k0 + kq]);
            As[kq + 0][r] = av.x; As[kq + 1][r] = av.y;
            As[kq + 2][r] = av.z; As[kq + 3][r] = av.w;
            const float4 wv = *reinterpret_cast<const float4*>(&W[(size_t)(n0 + r) * K + k0 + kq]);
            Ws[kq + 0][r] = wv.x; Ws[kq + 1][r] = wv.y;
            Ws[kq + 2][r] = wv.z; Ws[kq + 3][r] = wv.w;
        }
        __syncthreads();
        #pragma unroll
        for (int kk = 0; kk < 16; ++kk) {
            float a[8], b[8];
            *reinterpret_cast<float4*>(&a[0]) = *reinterpret_cast<const float4*>(&As[kk][ty * 8]);
            *reinterpret_cast<float4*>(&a[4]) = *reinterpret_cast<const float4*>(&As[kk][ty * 8 + 4]);
            *reinterpret_cast<float4*>(&b[0]) = *reinterpret_cast<const float4*>(&Ws[kk][tx * 8]);
            *reinterpret_cast<float4*>(&b[4]) = *reinterpret_cast<const float4*>(&Ws[kk][tx * 8 + 4]);
            #pragma unroll
            for (int i = 0; i < 8; ++i)
                #pragma unroll
                for (int j = 0; j < 8; ++j)
                    acc[i][j] = fmaf(a[i], b[j], acc[i][j]);
        }
        __syncthreads();
    }
    float bv[8];
    #pragma unroll
    for (int j = 0; j < 8; ++j) bv[j] = bias[n0 + tx * 8 + j];
    #pragma unroll
    for (int i = 0; i < 8; ++i) {
        const int m = m0 + ty * 8 + i;
        float* crow = &C[(size_t)m * 384 + n0 + tx * 8];
        float4 o0, o1;
        o0.x = acc[i][0] + bv[0]; o0.y = acc[i][1] + bv[1];
        o0.z = acc[i][2] + bv[2]; o0.w = acc[i][3] + bv[3];
        o1.x = acc[i][4] + bv[4]; o1.y = acc[i][5] + bv[5];
        o1.z = acc[i][6] + bv[6]; o1.w = acc[i][7] + bv[7];
        *reinterpret_cast<float4*>(&crow[0]) = o0;
        *reinterpret_cast<float4*>(&crow[4]) = o1;
    }
}

// ---------- GRU recurrent scan ----------
// One block per (dir, batch). 384 threads: thread j owns gate-row j of Whh
// (128 fp32 weights in VGPRs). h lives in LDS. Gate order (torch): r, z, n.
// xp already contains x@Wih^T + bih. Thread j computes dot(Whh[j], h) + bhh[j].
// Threads 0..127 -> r, 128..255 -> z, 256..383 -> n-path (holds hn + xn,
// reads r,z,h from LDS, updates h and writes the output).
__global__ __launch_bounds__(384, 1)
void gru_scan(const float* __restrict__ xpA, const float* __restrict__ xpB,
              const float* __restrict__ WA, const float* __restrict__ WB,
              const float* __restrict__ bA, const float* __restrict__ bB,
              int revA, int revB,
              float* __restrict__ seqout,   // x1 [B][T][256] or nullptr
              float* __restrict__ hfin)     // [B][H] or nullptr
{
    const int dir = blockIdx.y;
    const int b = blockIdx.x;
    const float* __restrict__ xp  = dir ? xpB : xpA;
    const float* __restrict__ Whh = dir ? WB : WA;
    const float* __restrict__ bhh = dir ? bB : bA;
    const int rev = dir ? revB : revA;
    const int j = threadIdx.x;

    __shared__ float h_s[H];
    __shared__ float r_s[H];
    __shared__ float z_s[H];

    float4 w[32];
    #pragma unroll
    for (int i = 0; i < 32; ++i)
        w[i] = *reinterpret_cast<const float4*>(&Whh[(size_t)j * H + i * 4]);
    const float bj = bhh[j];

    if (j < H) h_s[j] = 0.0f;
    __syncthreads();

    const int jtype = j >> 7;      // 0:r 1:z 2:n
    const int jj = j & (H - 1);

    int t = rev ? (T_SEQ - 1) : 0;
    const int tstep = rev ? -1 : 1;
    float xv = xp[((size_t)t * BATCH + b) * 384 + j];

    for (int s = 0; s < T_SEQ; ++s) {
        float xv_next = 0.0f;
        if (s + 1 < T_SEQ)
            xv_next = xp[((size_t)(t + tstep) * BATCH + b) * 384 + j];

        // dot(Whh[j], h) with 4 independent accumulator chains
        float a0 = 0.f, a1 = 0.f, a2 = 0.f, a3 = 0.f;
        #pragma unroll
        for (int i = 0; i < 32; ++i) {
            const float4 hv = *reinterpret_cast<const float4*>(&h_s[i * 4]);
            a0 = fmaf(w[i].x, hv.x, a0);
            a1 = fmaf(w[i].y, hv.y, a1);
            a2 = fmaf(w[i].z, hv.z, a2);
            a3 = fmaf(w[i].w, hv.w, a3);
        }
        const float g = ((a0 + a1) + (a2 + a3)) + bj;   // Whh_row.h + bhh

        if (jtype == 0)      r_s[jj] = sigmoid_f(g + xv);
        else if (jtype == 1) z_s[jj] = sigmoid_f(g + xv);
        __syncthreads();     // gates visible; all dot-reads of h done
        if (jtype == 2) {
            const float r = r_s[jj];
            const float z = z_s[jj];
            const float hp = h_s[jj];
            const float n = tanh_f(xv + r * g);         // xn + r*hn
            const float hn = fmaf(z, hp - n, n);        // (1-z)*n + z*hp
            h_s[jj] = hn;
            if (seqout)
                seqout[((size_t)b * T_SEQ + t) * 256 + (dir << 7) + jj] = hn;
        }
        __syncthreads();     // new h visible for next step
        xv = xv_next;
        t += tstep;
    }
    if (hfin && jtype == 2) hfin[(size_t)b * H + jj] = h_s[jj];
}

// ---------- decoder: mish -> LN -> Linear(128,128) -> mish -> LN -> Linear(128,1) ----------
__device__ __forceinline__ float block_sum128(float v, float* red) {
    #pragma unroll
    for (int o = 32; o > 0; o >>= 1) v += __shfl_down(v, o);
    const int w = threadIdx.x >> 6;
    if ((threadIdx.x & 63) == 0) red[w] = v;
    __syncthreads();
    const float s = red[0] + red[1];
    __syncthreads();
    return s;
}

__global__ __launch_bounds__(128, 1)
void decoder_kernel(const float* __restrict__ hb,
                    const float* __restrict__ g1, const float* __restrict__ be1,
                    const float* __restrict__ W1, const float* __restrict__ b1,
                    const float* __restrict__ g2, const float* __restrict__ be2,
                    const float* __restrict__ W2, const float* __restrict__ b2,
                    float* __restrict__ out)
{
    const int b = blockIdx.x;
    const int j = threadIdx.x;
    __shared__ float buf[H];
    __shared__ float red[2];

    const float m = mish_f(hb[(size_t)b * H + j]);
    const float mean = block_sum128(m, red) * (1.0f / H);
    const float d = m - mean;
    const float var = block_sum128(d * d, red) * (1.0f / H);
    const float y = d * rsqrtf(var + EPS) * g1[j] + be1[j];
    buf[j] = y;
    __syncthreads();

    float acc = b1[j];
    #pragma unroll
    for (int k = 0; k < H; k += 4) {
        const float4 wv = *reinterpret_cast<const float4*>(&W1[(size_t)j * H + k]);
        const float4 yv = *reinterpret_cast<const float4*>(&buf[k]);
        acc += wv.x * yv.x + wv.y * yv.y + wv.z * yv.z + wv.w * yv.w;
    }
    const float m2 = mish_f(acc);
    const float mean2 = block_sum128(m2, red) * (1.0f / H);
    const float d2 = m2 - mean2;
    const float var2 = block_sum128(d2 * d2, red) * (1.0f / H);
    const float y2 = d2 * rsqrtf(var2 + EPS) * g2[j] + be2[j];

    const float p = W2[j] * y2;
    const float s = block_sum128(p, red);
    if (j == 0) out[b] = s + b2[0];
}

// ---------- launch ----------
extern "C" void kernel_launch(void* const* d_in, const int* in_sizes, int n_in,
                              void* d_out, int out_size, void* d_ws, size_t ws_size,
                              hipStream_t stream)
{
    (void)in_sizes; (void)n_in; (void)out_size; (void)ws_size;
    const float* x     = (const float*)d_in[0];
    const float* Wih0f = (const float*)d_in[1];
    const float* Whh0f = (const float*)d_in[2];
    const float* bih0f = (const float*)d_in[3];
    const float* bhh0f = (const float*)d_in[4];
    const float* Wih0b = (const float*)d_in[5];
    const float* Whh0b = (const float*)d_in[6];
    const float* bih0b = (const float*)d_in[7];
    const float* bhh0b = (const float*)d_in[8];
    // d_in[9..12] = layer-1 forward params: provably unused (hf discarded)
    const float* Wih1b = (const float*)d_in[13];
    const float* Whh1b = (const float*)d_in[14];
    const float* bih1b = (const float*)d_in[15];
    const float* bhh1b = (const float*)d_in[16];
    const float* g1  = (const float*)d_in[17];
    const float* be1 = (const float*)d_in[18];
    const float* W1  = (const float*)d_in[19];
    const float* b1  = (const float*)d_in[20];
    const float* g2  = (const float*)d_in[21];
    const float* be2 = (const float*)d_in[22];
    const float* W2  = (const float*)d_in[23];
    const float* b2  = (const float*)d_in[24];
    float* out = (float*)d_out;

    float* ws = (float*)d_ws;
    const size_t XP_ELEMS = (size_t)T_SEQ * BATCH * 384;   // 50,331,648
    const size_t X1_ELEMS = (size_t)BATCH * T_SEQ * 256;   // 33,554,432
    float* xp0f = ws;
    float* xp0b = xp0f + XP_ELEMS;
    float* x1   = xp0b + XP_ELEMS;
    float* hbuf = x1 + X1_ELEMS;
    float* xp1b = xp0f;   // xp0f is dead after scan0 -> alias (peak ws ~537 MB)

    const dim3 pgrid(3, 1024);   // N=384/128, M=131072/128
    // Layer-0 input projections (x: K=512)
    proj_kernel<512><<<pgrid, 256, 0, stream>>>(x, Wih0f, bih0f, xp0f);
    proj_kernel<512><<<pgrid, 256, 0, stream>>>(x, Wih0b, bih0b, xp0b);
    // Layer-0 scans, both directions in one launch (128 blocks), write x1 = [of|ob]
    gru_scan<<<dim3(BATCH, 2), 384, 0, stream>>>(xp0f, xp0b, Whh0f, Whh0b, bhh0f, bhh0b,
                                                 0, 1, x1, nullptr);
    // Layer-1 backward input projection (x1: K=256)
    proj_kernel<256><<<pgrid, 256, 0, stream>>>(x1, Wih1b, bih1b, xp1b);
    // Layer-1 backward scan only (forward is dead code); final h -> hbuf
    gru_scan<<<dim3(BATCH, 1), 384, 0, stream>>>(xp1b, xp1b, Whh1b, Whh1b, bhh1b, bhh1b,
                                                 1, 1, nullptr, hbuf);
    // Decoder head
    decoder_kernel<<<64, 128, 0, stream>>>(hbuf, g1, be1, W1, b1, g2, be2, W2, b2, out);
}